// Round 6
// baseline (126.509 us; speedup 1.0000x reference)
//
#include <hip/hip_runtime.h>
#include <hip/hip_bf16.h>

// CumulativeLayerNorm fused single-pass: x [B=8, C=512, T=16000] f32.
// One block per (batch b, t-chunk of 32). 512 threads; each thread holds an
// 8 x f32x4 slice of the 512x32 tile in REGISTERS (32 VGPR) -> 4 blocks/CU.
// Column sums via in-wave shfl_xor + tiny LDS stage; global cumulative carry
// via decoupled-lookback aggregates (fixed-order tree sum => deterministic);
// normalize from registers, nontemporal stores. x is read ONCE.
// Workspace: W1[B*500] + W2[B*500] u64 {flag,val} (memset 0 each launch).

constexpr int Bb = 8;
constexpr int Cc = 512;
constexpr int Tt = 16000;
constexpr int T4 = Tt / 4;          // 4000
constexpr int TCH = 32;             // t per chunk
constexpr int T4CH = TCH / 4;       // 8
constexpr int NCHK = Tt / TCH;      // 500
constexpr float EPSF = 1e-8f;

typedef float f32x4 __attribute__((ext_vector_type(4)));

__device__ __forceinline__ unsigned long long pack_av(float v) {
    return (1ull << 32) | (unsigned long long)__float_as_uint(v);
}

__device__ __forceinline__ f32x4 shflx(f32x4 v, int m) {
    f32x4 r;
    r.x = __shfl_xor(v.x, m, 64);
    r.y = __shfl_xor(v.y, m, 64);
    r.z = __shfl_xor(v.z, m, 64);
    r.w = __shfl_xor(v.w, m, 64);
    return r;
}

// Sum aggregates W[chain][0..k-1] in FIXED order (64-lane slices + xor tree)
// -> deterministic. Spins until each predecessor has published.
__device__ __forceinline__ float lookback_sum(const unsigned long long* W,
                                              int chain_base, int k, int lane)
{
    float carry = 0.f;
    #pragma unroll 1
    for (int base = 0; base < k; base += 64) {
        const int j = base + lane;
        float v = 0.f;
        if (j < k) {
            unsigned long long w;
            for (;;) {
                w = __hip_atomic_load(&W[chain_base + j], __ATOMIC_RELAXED,
                                      __HIP_MEMORY_SCOPE_AGENT);
                if (w >> 32) break;
                __builtin_amdgcn_s_sleep(1);
            }
            v = __uint_as_float((unsigned)w);
        }
        #pragma unroll
        for (int m = 1; m < 64; m <<= 1) v += __shfl_xor(v, m, 64);
        carry += v;
    }
    return carry;
}

__global__ __launch_bounds__(512, 8)
void fused_cln_kernel(const float* __restrict__ x,
                      const float* __restrict__ gamma,
                      const float* __restrict__ beta,
                      float* __restrict__ out,
                      unsigned long long* __restrict__ W1,
                      unsigned long long* __restrict__ W2)
{
    const int bid = blockIdx.x;
    const int k = bid >> 3;          // chunk 0..499 (k-major: chains advance together)
    const int b = bid & 7;
    const int tid = threadIdx.x;
    const int c_sub = tid >> 3;      // 0..63
    const int t4s   = tid & 7;       // 0..7
    const int lane  = tid & 63;
    const int wave  = tid >> 6;      // 0..7

    __shared__ float gam[Cc], bet[Cc];
    gam[tid] = gamma[tid];
    bet[tid] = beta[tid];

    // ---------- phase A: tile -> registers, partial sums ----------
    const f32x4* xb = (const f32x4*)x + (size_t)(b * Cc + c_sub) * T4 + k * T4CH + t4s;
    f32x4 xr[8];
    #pragma unroll
    for (int r = 0; r < 8; ++r) xr[r] = xb[(size_t)r * 64 * T4];

    f32x4 ps = 0, pq = 0;
    #pragma unroll
    for (int r = 0; r < 8; ++r) { ps += xr[r]; pq += xr[r] * xr[r]; }

    // in-wave reduce over the 8 c_sub groups (t4s preserved by xor of multiples of 8)
    #pragma unroll
    for (int m = 8; m < 64; m <<= 1) { ps += shflx(ps, m); pq += shflx(pq, m); }

    __shared__ f32x4 red_s[8][8], red_q[8][8];   // [wave][t4s]
    if (lane < 8) { red_s[wave][lane] = ps; red_q[wave][lane] = pq; }
    __syncthreads();

    // ---------- phase B: wave 0 scans 32 t's + global lookback ----------
    __shared__ f32x4 mean_l[8], istd_l[8];

    if (tid < 64) {
        // gather: total over waves for t4s = lane&7 (fixed xor-tree order)
        f32x4 sv = red_s[lane >> 3][lane & 7];
        f32x4 qv = red_q[lane >> 3][lane & 7];
        #pragma unroll
        for (int m = 8; m < 64; m <<= 1) { sv += shflx(sv, m); qv += shflx(qv, m); }

        const bool act = lane < 8;
        const int chain = b * NCHK;

        const float c0 = sv.x, c1 = c0 + sv.y, c2 = c1 + sv.z, c3 = c2 + sv.w;
        float lsum = act ? c3 : 0.f;
        float sc = lsum;
        #pragma unroll
        for (int off = 1; off < 8; off <<= 1) {
            const float n = __shfl_up(sc, off, 64);
            if (lane >= off) sc += n;
        }
        const float total1 = __shfl(sc, 7, 64);
        const float ex1 = sc - lsum;

        if (lane == 0)
            __hip_atomic_store(&W1[chain + k], pack_av(total1), __ATOMIC_RELAXED,
                               __HIP_MEMORY_SCOPE_AGENT);
        const float carry1 = lookback_sum(W1, chain, k, lane);

        const float t0f = (float)(k * TCH + lane * 4);
        f32x4 cnt;
        cnt.x = (float)Cc * (t0f + 1.f);
        cnt.y = (float)Cc * (t0f + 2.f);
        cnt.z = (float)Cc * (t0f + 3.f);
        cnt.w = (float)Cc * (t0f + 4.f);

        f32x4 cs1;
        cs1.x = carry1 + ex1 + c0;
        cs1.y = carry1 + ex1 + c1;
        cs1.z = carry1 + ex1 + c2;
        cs1.w = carry1 + ex1 + c3;
        const f32x4 mn = cs1 / cnt;
        if (act) mean_l[lane] = mn;

        f32x4 s2 = qv - 2.f * mn * sv + (float)Cc * mn * mn;
        if (!act) s2 = 0.f;

        const float d0 = s2.x, d1 = d0 + s2.y, d2 = d1 + s2.z, d3 = d2 + s2.w;
        float lsum2 = act ? d3 : 0.f;
        float sc2 = lsum2;
        #pragma unroll
        for (int off = 1; off < 8; off <<= 1) {
            const float n = __shfl_up(sc2, off, 64);
            if (lane >= off) sc2 += n;
        }
        const float total2 = __shfl(sc2, 7, 64);
        const float ex2 = sc2 - lsum2;

        if (lane == 0)
            __hip_atomic_store(&W2[chain + k], pack_av(total2), __ATOMIC_RELAXED,
                               __HIP_MEMORY_SCOPE_AGENT);
        const float carry2 = lookback_sum(W2, chain, k, lane);

        if (act) {
            f32x4 cs2;
            cs2.x = carry2 + ex2 + d0;
            cs2.y = carry2 + ex2 + d1;
            cs2.z = carry2 + ex2 + d2;
            cs2.w = carry2 + ex2 + d3;
            const f32x4 var = cs2 / cnt;
            f32x4 is;
            is.x = rsqrtf(var.x + EPSF);
            is.y = rsqrtf(var.y + EPSF);
            is.z = rsqrtf(var.z + EPSF);
            is.w = rsqrtf(var.w + EPSF);
            istd_l[lane] = is;
        }
    }
    __syncthreads();

    // ---------- phase C: normalize from registers, stream out ----------
    const f32x4 m4 = mean_l[t4s];
    const f32x4 s4 = istd_l[t4s];
    f32x4* ob = (f32x4*)out + (size_t)(b * Cc + c_sub) * T4 + k * T4CH + t4s;
    #pragma unroll
    for (int r = 0; r < 8; ++r) {
        const int c = c_sub + 64 * r;
        const f32x4 sg   = s4 * gam[c];
        const f32x4 off4 = bet[c] - m4 * sg;
        __builtin_nontemporal_store(xr[r] * sg + off4, &ob[(size_t)r * 64 * T4]);
    }
}

extern "C" void kernel_launch(void* const* d_in, const int* in_sizes, int n_in,
                              void* d_out, int out_size, void* d_ws, size_t ws_size,
                              hipStream_t stream) {
    const float* x     = (const float*)d_in[0];
    const float* gamma = (const float*)d_in[1];
    const float* beta  = (const float*)d_in[2];
    float* out = (float*)d_out;

    unsigned long long* W1 = (unsigned long long*)d_ws;
    unsigned long long* W2 = W1 + (size_t)Bb * NCHK;

    // clear lookback state every launch (ws is NOT re-poisoned between replays)
    hipMemsetAsync(d_ws, 0, 2 * (size_t)Bb * NCHK * sizeof(unsigned long long), stream);

    fused_cln_kernel<<<Bb * NCHK, 512, 0, stream>>>(x, gamma, beta, out, W1, W2);
}

// Round 7
// 123.421 us; speedup vs baseline: 1.0250x; 1.0250x over previous
//
#include <hip/hip_runtime.h>
#include <hip/hip_bf16.h>

// CumulativeLayerNorm fused single-pass: x [B=8, C=512, T=16000] f32.
// One block per (batch b, t-chunk of 32). 512 threads. The 512x32 x-tile is
// staged in LDS (padded, conflict-free) so it is GUARANTEED resident across
// the global-scan dependency (compiler kept dropping register tiles).
// Column sums from load registers; global cumulative carry via
// decoupled-lookback aggregates (fixed-order tree sum => deterministic);
// normalize from LDS, nontemporal stores. x is read from HBM exactly once.
// Workspace: W1[B*500] + W2[B*500] u64 {flag,val} (memset 0 each launch).

constexpr int Bb = 8;
constexpr int Cc = 512;
constexpr int Tt = 16000;
constexpr int T4 = Tt / 4;          // 4000
constexpr int TCH = 32;             // t per chunk
constexpr int T4CH = TCH / 4;       // 8
constexpr int NCHK = Tt / TCH;      // 500
constexpr int LDP = T4CH + 1;       // padded row stride in f32x4 (9)
constexpr float EPSF = 1e-8f;

typedef float f32x4 __attribute__((ext_vector_type(4)));

__device__ __forceinline__ unsigned long long pack_av(float v) {
    return (1ull << 32) | (unsigned long long)__float_as_uint(v);
}

__device__ __forceinline__ f32x4 shflx(f32x4 v, int m) {
    f32x4 r;
    r.x = __shfl_xor(v.x, m, 64);
    r.y = __shfl_xor(v.y, m, 64);
    r.z = __shfl_xor(v.z, m, 64);
    r.w = __shfl_xor(v.w, m, 64);
    return r;
}

// Sum aggregates W[chain][0..k-1] in FIXED order (64-lane slices + xor tree)
// -> deterministic. Spins until each predecessor has published.
__device__ __forceinline__ float lookback_sum(const unsigned long long* W,
                                              int chain_base, int k, int lane)
{
    float carry = 0.f;
    #pragma unroll 1
    for (int base = 0; base < k; base += 64) {
        const int j = base + lane;
        float v = 0.f;
        if (j < k) {
            unsigned long long w;
            for (;;) {
                w = __hip_atomic_load(&W[chain_base + j], __ATOMIC_RELAXED,
                                      __HIP_MEMORY_SCOPE_AGENT);
                if (w >> 32) break;
                __builtin_amdgcn_s_sleep(1);
            }
            v = __uint_as_float((unsigned)w);
        }
        #pragma unroll
        for (int m = 1; m < 64; m <<= 1) v += __shfl_xor(v, m, 64);
        carry += v;
    }
    return carry;
}

__global__ __launch_bounds__(512, 4)
void fused_cln_kernel(const float* __restrict__ x,
                      const float* __restrict__ gamma,
                      const float* __restrict__ beta,
                      float* __restrict__ out,
                      unsigned long long* __restrict__ W1,
                      unsigned long long* __restrict__ W2)
{
    const int bid = blockIdx.x;
    const int k = bid >> 3;          // chunk 0..499 (k-major: chains advance together)
    const int b = bid & 7;
    const int tid = threadIdx.x;
    const int c_sub = tid >> 3;      // 0..63
    const int t4s   = tid & 7;       // 0..7
    const int lane  = tid & 63;
    const int wave  = tid >> 6;      // 0..7

    __shared__ f32x4 tile[Cc * LDP];            // 73,728 B, padded: no bank conflicts
    __shared__ f32x4 red_s[8][8], red_q[8][8];  // [wave][t4s]
    __shared__ f32x4 mean_l[8], istd_l[8];

    // ---------- phase A: load tile -> LDS (+ partial sums from registers) ----------
    const f32x4* xb = (const f32x4*)x + (size_t)(b * Cc + c_sub) * T4 + k * T4CH + t4s;
    f32x4 v[8];
    #pragma unroll
    for (int r = 0; r < 8; ++r) v[r] = xb[(size_t)r * 64 * T4];

    f32x4 ps = 0, pq = 0;
    #pragma unroll
    for (int r = 0; r < 8; ++r) {
        ps += v[r];
        pq += v[r] * v[r];
        tile[(c_sub + 64 * r) * LDP + t4s] = v[r];
    }

    // in-wave reduce over the 8 c_sub groups (t4s preserved: xor of multiples of 8)
    #pragma unroll
    for (int m = 8; m < 64; m <<= 1) { ps += shflx(ps, m); pq += shflx(pq, m); }
    if (lane < 8) { red_s[wave][lane] = ps; red_q[wave][lane] = pq; }
    __syncthreads();

    // ---------- phase B: wave 0 scans 32 t's + global lookback ----------
    if (tid < 64) {
        // gather: total over waves for t4s = lane&7 (fixed xor-tree order)
        f32x4 sv = red_s[lane >> 3][lane & 7];
        f32x4 qv = red_q[lane >> 3][lane & 7];
        #pragma unroll
        for (int m = 8; m < 64; m <<= 1) { sv += shflx(sv, m); qv += shflx(qv, m); }

        const bool act = lane < 8;
        const int chain = b * NCHK;

        const float c0 = sv.x, c1 = c0 + sv.y, c2 = c1 + sv.z, c3 = c2 + sv.w;
        float lsum = act ? c3 : 0.f;
        float sc = lsum;
        #pragma unroll
        for (int off = 1; off < 8; off <<= 1) {
            const float n = __shfl_up(sc, off, 64);
            if (lane >= off) sc += n;
        }
        const float total1 = __shfl(sc, 7, 64);
        const float ex1 = sc - lsum;

        if (lane == 0)
            __hip_atomic_store(&W1[chain + k], pack_av(total1), __ATOMIC_RELAXED,
                               __HIP_MEMORY_SCOPE_AGENT);
        const float carry1 = lookback_sum(W1, chain, k, lane);

        const float t0f = (float)(k * TCH + lane * 4);
        f32x4 cnt;
        cnt.x = (float)Cc * (t0f + 1.f);
        cnt.y = (float)Cc * (t0f + 2.f);
        cnt.z = (float)Cc * (t0f + 3.f);
        cnt.w = (float)Cc * (t0f + 4.f);

        f32x4 cs1;
        cs1.x = carry1 + ex1 + c0;
        cs1.y = carry1 + ex1 + c1;
        cs1.z = carry1 + ex1 + c2;
        cs1.w = carry1 + ex1 + c3;
        const f32x4 mn = cs1 / cnt;
        if (act) mean_l[lane] = mn;

        f32x4 s2 = qv - 2.f * mn * sv + (float)Cc * mn * mn;
        if (!act) s2 = 0.f;

        const float d0 = s2.x, d1 = d0 + s2.y, d2 = d1 + s2.z, d3 = d2 + s2.w;
        float lsum2 = act ? d3 : 0.f;
        float sc2 = lsum2;
        #pragma unroll
        for (int off = 1; off < 8; off <<= 1) {
            const float n = __shfl_up(sc2, off, 64);
            if (lane >= off) sc2 += n;
        }
        const float total2 = __shfl(sc2, 7, 64);
        const float ex2 = sc2 - lsum2;

        if (lane == 0)
            __hip_atomic_store(&W2[chain + k], pack_av(total2), __ATOMIC_RELAXED,
                               __HIP_MEMORY_SCOPE_AGENT);
        const float carry2 = lookback_sum(W2, chain, k, lane);

        if (act) {
            f32x4 cs2;
            cs2.x = carry2 + ex2 + d0;
            cs2.y = carry2 + ex2 + d1;
            cs2.z = carry2 + ex2 + d2;
            cs2.w = carry2 + ex2 + d3;
            const f32x4 var = cs2 / cnt;
            f32x4 is;
            is.x = rsqrtf(var.x + EPSF);
            is.y = rsqrtf(var.y + EPSF);
            is.z = rsqrtf(var.z + EPSF);
            is.w = rsqrtf(var.w + EPSF);
            istd_l[lane] = is;
        }
    }
    __syncthreads();

    // ---------- phase C: normalize from LDS, stream out ----------
    const f32x4 m4 = mean_l[t4s];
    const f32x4 s4 = istd_l[t4s];
    f32x4* ob = (f32x4*)out + (size_t)(b * Cc + c_sub) * T4 + k * T4CH + t4s;
    #pragma unroll
    for (int r = 0; r < 8; ++r) {
        const int c = c_sub + 64 * r;
        const f32x4 sg   = s4 * gamma[c];
        const f32x4 off4 = beta[c] - m4 * sg;
        const f32x4 xv   = tile[c * LDP + t4s];
        __builtin_nontemporal_store(xv * sg + off4, &ob[(size_t)r * 64 * T4]);
    }
}

extern "C" void kernel_launch(void* const* d_in, const int* in_sizes, int n_in,
                              void* d_out, int out_size, void* d_ws, size_t ws_size,
                              hipStream_t stream) {
    const float* x     = (const float*)d_in[0];
    const float* gamma = (const float*)d_in[1];
    const float* beta  = (const float*)d_in[2];
    float* out = (float*)d_out;

    unsigned long long* W1 = (unsigned long long*)d_ws;
    unsigned long long* W2 = W1 + (size_t)Bb * NCHK;

    // clear lookback state every launch (ws is NOT re-poisoned between replays)
    hipMemsetAsync(d_ws, 0, 2 * (size_t)Bb * NCHK * sizeof(unsigned long long), stream);

    fused_cln_kernel<<<Bb * NCHK, 512, 0, stream>>>(x, gamma, beta, out, W1, W2);
}